// Round 1
// 253.146 us; speedup vs baseline: 1.0133x; 1.0133x over previous
//
#include <hip/hip_runtime.h>
#include <math.h>

#define Cn 256
#define Ln 256
#define Bn 2
#define H1 1024
#define NIDX 64
#define NREL 128
#define NCOMBO 16384
#define BK 64
#define TROWS 32

typedef __attribute__((ext_vector_type(8))) short bf16x8;
typedef __attribute__((ext_vector_type(4))) float f32x4;
typedef unsigned int u32;

__device__ __forceinline__ float gelu_exact(float x) {
    return 0.5f * x * (1.0f + erff(x * 0.70710678118654752f));
}
__device__ __forceinline__ short f2bf(float f) {
    unsigned u = __float_as_uint(f);
    return (short)((u + 0x7fffu + ((u >> 16) & 1u)) >> 16);   // RNE
}
// async global->LDS, 16B/lane. lds base must be wave-uniform; HW adds lane*16.
__device__ __forceinline__ void async16(const void* g, void* l) {
    __builtin_amdgcn_global_load_lds((const __attribute__((address_space(1))) u32*)g,
                                     (__attribute__((address_space(3))) u32*)l, 16, 0, 0);
}

// ---------------- mod = silu(c) @ ada_w^T + ada_b -> (B, 3C) ----------------
__global__ __launch_bounds__(256) void mod_kernel(
    const float* __restrict__ c_BD, const float* __restrict__ ada_w,
    const float* __restrict__ ada_b, float* __restrict__ mod)
{
    int o = blockIdx.x * 256 + threadIdx.x;
    int b = o / (3 * Cn);
    int j = o - b * (3 * Cn);
    const float* crow = c_BD + b * Cn;
    const float* wrow = ada_w + (size_t)j * Cn;
    float acc = 0.f;
    for (int k = 0; k < Cn; k += 4) {
        float4 cv = *(const float4*)(crow + k);
        float4 wv = *(const float4*)(wrow + k);
        acc += (cv.x / (1.f + expf(-cv.x))) * wv.x;
        acc += (cv.y / (1.f + expf(-cv.y))) * wv.y;
        acc += (cv.z / (1.f + expf(-cv.z))) * wv.z;
        acc += (cv.w / (1.f + expf(-cv.w))) * wv.w;
    }
    mod[o] = acc + ada_b[j];
}

// ---------------- fp32 -> bf16 weight conversion ----------------
__global__ __launch_bounds__(256) void cvt_kernel(
    const float* __restrict__ s, short* __restrict__ d, int n)
{
    int i = (blockIdx.x * 256 + threadIdx.x) * 4;
    if (i < n) {
        float4 v = *(const float4*)(s + i);
        short4 o;
        o.x = f2bf(v.x); o.y = f2bf(v.y); o.z = f2bf(v.z); o.w = f2bf(v.w);
        *(short4*)(d + i) = o;
    }
}

// ---------------- LN: h bf16 [16384][256] (s recomputed later, no store) ----
// lane handles 4 CONSECUTIVE channels -> short4 coalesced stores.
__global__ __launch_bounds__(256) void ln_kernel(
    const float* __restrict__ embed_w, const float* __restrict__ pos_w,
    const float* __restrict__ ln_g, const float* __restrict__ ln_b,
    const float* __restrict__ mod, short* __restrict__ h_out)
{
    const int tid  = threadIdx.x;
    const int wave = tid >> 6;
    const int lane = tid & 63;
    const int base = blockIdx.x * 8;          // 8 combo rows / block
    const int b    = base >> 13;
    const int idx  = (base >> 7) & 63;
    const int rel0 = base & 127;
    const float* modb = mod + b * (3 * Cn);
    const int c0 = lane * 4;

    const float4 ev = *(const float4*)(embed_w + (size_t)idx * Cn + c0);
    const float4 sc = *(const float4*)(modb + Cn + c0);
    const float4 sh = *(const float4*)(modb + c0);
    const float4 lg = *(const float4*)(ln_g + c0);
    const float4 lb = *(const float4*)(ln_b + c0);

    #pragma unroll
    for (int r8 = 0; r8 < 2; ++r8) {
        const int rr  = wave * 2 + r8;        // 0..7
        const int row = base + rr;
        const float4 p = *(const float4*)(pos_w + (size_t)(rel0 + rr) * Cn + c0);
        float v0 = (ev.x + p.x) * (1.f + sc.x) + sh.x;
        float v1 = (ev.y + p.y) * (1.f + sc.y) + sh.y;
        float v2 = (ev.z + p.z) * (1.f + sc.z) + sh.z;
        float v3 = (ev.w + p.w) * (1.f + sc.w) + sh.w;
        float sum = v0 + v1 + v2 + v3;
        #pragma unroll
        for (int off = 32; off; off >>= 1) sum += __shfl_xor(sum, off, 64);
        const float mu = sum * (1.f / Cn);
        float t0 = v0 - mu, t1 = v1 - mu, t2 = v2 - mu, t3 = v3 - mu;
        float p2 = t0 * t0 + t1 * t1 + t2 * t2 + t3 * t3;
        #pragma unroll
        for (int off = 32; off; off >>= 1) p2 += __shfl_xor(p2, off, 64);
        const float rstd = rsqrtf(p2 * (1.f / Cn) + 1e-5f);

        short4 hq;
        hq.x = f2bf(t0 * rstd * lg.x + lb.x);
        hq.y = f2bf(t1 * rstd * lg.y + lb.y);
        hq.z = f2bf(t2 * rstd * lg.z + lb.z);
        hq.w = f2bf(t3 * rstd * lg.w + lb.w);
        *(short4*)(h_out + (size_t)row * Cn + c0) = hq;
    }
}

// ---------------- GEMM1: g[16384,1024] = gelu(h @ w1^T + b1), bf16 out ------
// 128x128 tile, BK=64, weights as A-operand -> lane owns 4 consecutive n.
// T2 XOR-swizzle: LDS row stride 128B; source chunk pre-swizzled (rule #21),
// read applies same XOR. Spreads each ks over all 32 banks.
__global__ __launch_bounds__(256) void gemm1_kernel(
    const short* __restrict__ h, const short* __restrict__ w1,
    const float* __restrict__ fc1_b, short* __restrict__ g)
{
    __shared__ __align__(16) short Alds[128 * BK];   // h tile [128 m][64 k]
    __shared__ __align__(16) short Wlds[128 * BK];   // w1 tile [128 n][64 k]

    const int tid  = threadIdx.x;
    const int wave = tid >> 6;
    const int lane = tid & 63;
    const int quad = lane >> 4;
    const int l15  = lane & 15;
    const int wm   = wave >> 1, wn = wave & 1;
    const int m0 = (blockIdx.x >> 3) * 128;
    const int n0 = (blockIdx.x & 7) * 128;

    const int srow = lane >> 3;                  // staging row within 8-row chunk
    const int skel = ((lane & 7) ^ srow) * 8;    // XOR-swizzled source chunk

    f32x4 acc[4][4];
    #pragma unroll
    for (int a = 0; a < 4; ++a)
        #pragma unroll
        for (int c = 0; c < 4; ++c) acc[a][c] = (f32x4){0.f, 0.f, 0.f, 0.f};

    for (int kt = 0; kt < Cn; kt += BK) {
        #pragma unroll
        for (int c = 0; c < 4; ++c) {
            const int r = wave * 32 + c * 8;
            async16(h  + (size_t)(m0 + r + srow) * Cn + kt + skel, Alds + r * BK);
            async16(w1 + (size_t)(n0 + r + srow) * Cn + kt + skel, Wlds + r * BK);
        }
        __syncthreads();
        #pragma unroll
        for (int ks = 0; ks < 2; ++ks) {
            const int swz = ((((ks << 2) | quad) ^ (l15 & 7)) << 3);  // shorts
            bf16x8 wf[4], hf[4];
            #pragma unroll
            for (int nt = 0; nt < 4; ++nt)
                wf[nt] = *(const bf16x8*)(Wlds + (wn * 64 + nt * 16 + l15) * BK + swz);
            #pragma unroll
            for (int mt = 0; mt < 4; ++mt)
                hf[mt] = *(const bf16x8*)(Alds + (wm * 64 + mt * 16 + l15) * BK + swz);
            #pragma unroll
            for (int mt = 0; mt < 4; ++mt)
                #pragma unroll
                for (int nt = 0; nt < 4; ++nt)
                    acc[mt][nt] = __builtin_amdgcn_mfma_f32_16x16x32_bf16(
                        wf[nt], hf[mt], acc[mt][nt], 0, 0, 0);
        }
        __syncthreads();
    }

    // D layout (weights as A): row=n=quad*4+r, col=m=l15 -> short4 per tile
    #pragma unroll
    for (int mt = 0; mt < 4; ++mt) {
        const int m = m0 + wm * 64 + mt * 16 + l15;
        #pragma unroll
        for (int nt = 0; nt < 4; ++nt) {
            const int n = n0 + wn * 64 + nt * 16 + quad * 4;
            const float4 b4 = *(const float4*)(fc1_b + n);
            short4 o;
            o.x = f2bf(gelu_exact(acc[mt][nt][0] + b4.x));
            o.y = f2bf(gelu_exact(acc[mt][nt][1] + b4.y));
            o.z = f2bf(gelu_exact(acc[mt][nt][2] + b4.z));
            o.w = f2bf(gelu_exact(acc[mt][nt][3] + b4.w));
            *(short4*)(g + (size_t)m * H1 + n) = o;
        }
    }
}

// ---------------- GEMM2: table[16384,256] = s + gate*(g @ w2^T + b2) --------
// 64x128 tile, BK=64, K=1024. s recomputed in epilogue (no sbuf traffic).
__global__ __launch_bounds__(256) void gemm2_kernel(
    const short* __restrict__ g, const short* __restrict__ w2,
    const float* __restrict__ fc2_b,
    const float* __restrict__ embed_w, const float* __restrict__ pos_w,
    const float* __restrict__ mod, float* __restrict__ table)
{
    __shared__ __align__(16) short Alds[64 * BK];    // g tile [64 m][64 k]
    __shared__ __align__(16) short Wlds[128 * BK];   // w2 tile [128 n][64 k]

    const int tid  = threadIdx.x;
    const int wave = tid >> 6;
    const int lane = tid & 63;
    const int quad = lane >> 4;
    const int l15  = lane & 15;
    const int wm   = wave >> 1, wn = wave & 1;
    const int m0 = (blockIdx.x >> 1) * 64;
    const int n0 = (blockIdx.x & 1) * 128;
    const int b  = m0 >> 13;
    const float* modb = mod + b * (3 * Cn);

    const int srow = lane >> 3;
    const int skel = ((lane & 7) ^ srow) * 8;    // XOR-swizzled source chunk

    f32x4 acc[2][4];
    #pragma unroll
    for (int a = 0; a < 2; ++a)
        #pragma unroll
        for (int c = 0; c < 4; ++c) acc[a][c] = (f32x4){0.f, 0.f, 0.f, 0.f};

    for (int kt = 0; kt < H1; kt += BK) {
        #pragma unroll
        for (int c = 0; c < 2; ++c) {
            const int r = wave * 16 + c * 8;
            async16(g + (size_t)(m0 + r + srow) * H1 + kt + skel, Alds + r * BK);
        }
        #pragma unroll
        for (int c = 0; c < 4; ++c) {
            const int r = wave * 32 + c * 8;
            async16(w2 + (size_t)(n0 + r + srow) * H1 + kt + skel, Wlds + r * BK);
        }
        __syncthreads();
        #pragma unroll
        for (int ks = 0; ks < 2; ++ks) {
            const int swz = ((((ks << 2) | quad) ^ (l15 & 7)) << 3);  // shorts
            bf16x8 wf[4], gf[2];
            #pragma unroll
            for (int nt = 0; nt < 4; ++nt)
                wf[nt] = *(const bf16x8*)(Wlds + (wn * 64 + nt * 16 + l15) * BK + swz);
            #pragma unroll
            for (int mt = 0; mt < 2; ++mt)
                gf[mt] = *(const bf16x8*)(Alds + (wm * 32 + mt * 16 + l15) * BK + swz);
            #pragma unroll
            for (int mt = 0; mt < 2; ++mt)
                #pragma unroll
                for (int nt = 0; nt < 4; ++nt)
                    acc[mt][nt] = __builtin_amdgcn_mfma_f32_16x16x32_bf16(
                        wf[nt], gf[mt], acc[mt][nt], 0, 0, 0);
        }
        __syncthreads();
    }

    #pragma unroll
    for (int mt = 0; mt < 2; ++mt) {
        const int m = m0 + wm * 32 + mt * 16 + l15;
        const int eidx = (m >> 7) & 63;
        const int rel  = m & 127;
        const float* erow = embed_w + (size_t)eidx * Cn;
        const float* prow = pos_w + (size_t)rel * Cn;
        #pragma unroll
        for (int nt = 0; nt < 4; ++nt) {
            const int n = n0 + wn * 64 + nt * 16 + quad * 4;
            const float4 b4 = *(const float4*)(fc2_b + n);
            const float4 g4 = *(const float4*)(modb + 2 * Cn + n);
            const float4 sc = *(const float4*)(modb + Cn + n);
            const float4 sh = *(const float4*)(modb + n);
            const float4 e4 = *(const float4*)(erow + n);
            const float4 p4 = *(const float4*)(prow + n);
            float4 o;
            float s;
            s   = (e4.x + p4.x) * (1.f + sc.x) + sh.x;
            o.x = s + g4.x * (acc[mt][nt][0] + b4.x);
            s   = (e4.y + p4.y) * (1.f + sc.y) + sh.y;
            o.y = s + g4.y * (acc[mt][nt][1] + b4.y);
            s   = (e4.z + p4.z) * (1.f + sc.z) + sh.z;
            o.z = s + g4.z * (acc[mt][nt][2] + b4.z);
            s   = (e4.w + p4.w) * (1.f + sc.w) + sh.w;
            o.w = s + g4.w * (acc[mt][nt][3] + b4.w);
            *(float4*)(table + (size_t)m * Cn + n) = o;
        }
    }
}

// ---------------- gather: out[b,i,j] = table[(b,idx,rel)] ----------------
__global__ __launch_bounds__(256) void gather_kernel(
    const float* __restrict__ x, const float* __restrict__ bins,
    const float* __restrict__ table, float* __restrict__ out)
{
    __shared__ float xs[Ln * 3];
    __shared__ float bins_s[63];
    __shared__ int   idx_s[64];

    const int tid = threadIdx.x;
    const int blk = blockIdx.x;          // (b*256 + i)*4 + q
    const int q   = blk & 3;
    const int bi  = blk >> 2;
    const int b   = bi >> 8;
    const int i   = bi & 255;

    for (int t = tid; t < Ln * 3; t += 256) xs[t] = x[(size_t)b * Ln * 3 + t];
    if (tid < 63) bins_s[tid] = bins[tid];
    __syncthreads();

    if (tid < 64) {
        int j = q * 64 + tid;
        float d0 = xs[3 * i]     - xs[3 * j];
        float d1 = xs[3 * i + 1] - xs[3 * j + 1];
        float d2 = xs[3 * i + 2] - xs[3 * j + 2];
        float d = d0 * d0 + d1 * d1 + d2 * d2;
        int v = 0;
        #pragma unroll
        for (int k = 0; k < 63; ++k) v += (bins_s[k] < d) ? 1 : 0;
        idx_s[tid] = v;
    }
    __syncthreads();

    const int wave = tid >> 6;
    const int lane = tid & 63;
    float4* outp = (float4*)(out + (size_t)bi * Ln * Cn);
    const float4* tab4 = (const float4*)table;

    float4 v[16];
    #pragma unroll
    for (int jj = 0; jj < 16; ++jj) {
        int jl  = wave * 16 + jj;
        int j   = q * 64 + jl;
        int rel = i - j;
        rel = (rel < -64 ? -64 : (rel > 63 ? 63 : rel)) + 64;
        size_t trow = (size_t)((b * NIDX + idx_s[jl]) * NREL + rel) * (Cn / 4);
        v[jj] = tab4[trow + lane];
    }
    #pragma unroll
    for (int jj = 0; jj < 16; ++jj) {
        int j = q * 64 + wave * 16 + jj;
        outp[(size_t)j * (Cn / 4) + lane] = v[jj];
    }
}

// ---------------- tier-B fallback: R3 fused MFMA table kernel ----------------
__global__ __launch_bounds__(256) void table_mfma_kernel(
    const float* __restrict__ embed_w, const float* __restrict__ pos_w,
    const float* __restrict__ ln_g, const float* __restrict__ ln_b,
    const short* __restrict__ fc1bf, const float* __restrict__ fc1_b,
    const short* __restrict__ fc2bf, const float* __restrict__ fc2_b,
    const float* __restrict__ mod, float* __restrict__ table)
{
    __shared__ __align__(16) short h_lds[TROWS][264];
    __shared__ __align__(16) short g_lds[TROWS][264];
    __shared__ float s_lds[TROWS][260];

    const int tid  = threadIdx.x;
    const int wave = tid >> 6;
    const int lane = tid & 63;
    const int quad = lane >> 4;
    const int l15  = lane & 15;

    const int base = blockIdx.x * TROWS;
    const int b    = base >> 13;
    const int idx  = (base >> 7) & 63;
    const int rel0 = base & 127;

    const float* modb = mod + b * (3 * Cn);
    const float* erow = embed_w + (size_t)idx * Cn;

    float scale[4], shift[4], lng[4], lnb[4], ev[4];
    #pragma unroll
    for (int m = 0; m < 4; ++m) {
        int c = lane + 64 * m;
        scale[m] = 1.f + modb[Cn + c];
        shift[m] = modb[c];
        lng[m]   = ln_g[c];
        lnb[m]   = ln_b[c];
        ev[m]    = erow[c];
    }

    for (int r8 = 0; r8 < 8; ++r8) {
        const int rr = wave * 8 + r8;
        const float* prow = pos_w + (size_t)(rel0 + rr) * Cn;
        float sv[4]; float sum = 0.f;
        #pragma unroll
        for (int m = 0; m < 4; ++m) {
            float v = (ev[m] + prow[lane + 64 * m]) * scale[m] + shift[m];
            sv[m] = v; sum += v;
        }
        #pragma unroll
        for (int off = 32; off; off >>= 1) sum += __shfl_xor(sum, off, 64);
        float mu = sum * (1.f / Cn);
        float p2 = 0.f;
        #pragma unroll
        for (int m = 0; m < 4; ++m) { float t = sv[m] - mu; p2 += t * t; }
        #pragma unroll
        for (int off = 32; off; off >>= 1) p2 += __shfl_xor(p2, off, 64);
        float rstd = rsqrtf(p2 * (1.f / Cn) + 1e-5f);
        #pragma unroll
        for (int m = 0; m < 4; ++m) {
            int c = lane + 64 * m;
            s_lds[rr][c] = sv[m];
            h_lds[rr][c] = f2bf((sv[m] - mu) * rstd * lng[m] + lnb[m]);
        }
    }
    __syncthreads();

    f32x4 acc2[2][4];
    #pragma unroll
    for (int mt = 0; mt < 2; ++mt)
        #pragma unroll
        for (int nt = 0; nt < 4; ++nt) acc2[mt][nt] = (f32x4){0.f, 0.f, 0.f, 0.f};

    for (int c = 0; c < 4; ++c) {
        f32x4 z[2][4];
        #pragma unroll
        for (int mt = 0; mt < 2; ++mt)
            #pragma unroll
            for (int nt = 0; nt < 4; ++nt) z[mt][nt] = (f32x4){0.f, 0.f, 0.f, 0.f};

        #pragma unroll
        for (int ks = 0; ks < 8; ++ks) {
            int k0 = ks * 32 + quad * 8;
            bf16x8 a0 = *(const bf16x8*)(&h_lds[l15][k0]);
            bf16x8 a1 = *(const bf16x8*)(&h_lds[16 + l15][k0]);
            #pragma unroll
            for (int nt = 0; nt < 4; ++nt) {
                int n = c * 256 + wave * 64 + nt * 16 + l15;
                bf16x8 bf = *(const bf16x8*)(fc1bf + (size_t)n * Cn + k0);
                z[0][nt] = __builtin_amdgcn_mfma_f32_16x16x32_bf16(a0, bf, z[0][nt], 0, 0, 0);
                z[1][nt] = __builtin_amdgcn_mfma_f32_16x16x32_bf16(a1, bf, z[1][nt], 0, 0, 0);
            }
        }
        __syncthreads();
        #pragma unroll
        for (int mt = 0; mt < 2; ++mt)
            #pragma unroll
            for (int nt = 0; nt < 4; ++nt) {
                int coll = wave * 64 + nt * 16 + l15;
                float bias = fc1_b[c * 256 + coll];
                #pragma unroll
                for (int r = 0; r < 4; ++r) {
                    int row = mt * 16 + quad * 4 + r;
                    g_lds[row][coll] = f2bf(gelu_exact(z[mt][nt][r] + bias));
                }
            }
        __syncthreads();
        #pragma unroll
        for (int ks = 0; ks < 8; ++ks) {
            int k0 = ks * 32 + quad * 8;
            bf16x8 a0 = *(const bf16x8*)(&g_lds[l15][k0]);
            bf16x8 a1 = *(const bf16x8*)(&g_lds[16 + l15][k0]);
            #pragma unroll
            for (int nt = 0; nt < 4; ++nt) {
                int n = wave * 64 + nt * 16 + l15;
                bf16x8 bf = *(const bf16x8*)(fc2bf + (size_t)n * H1 + c * 256 + k0);
                acc2[0][nt] = __builtin_amdgcn_mfma_f32_16x16x32_bf16(a0, bf, acc2[0][nt], 0, 0, 0);
                acc2[1][nt] = __builtin_amdgcn_mfma_f32_16x16x32_bf16(a1, bf, acc2[1][nt], 0, 0, 0);
            }
        }
    }

    #pragma unroll
    for (int nt = 0; nt < 4; ++nt) {
        int col = wave * 64 + nt * 16 + l15;
        float bias = fc2_b[col];
        float gate = modb[2 * Cn + col];
        #pragma unroll
        for (int mt = 0; mt < 2; ++mt)
            #pragma unroll
            for (int r = 0; r < 4; ++r) {
                int row = mt * 16 + quad * 4 + r;
                float v = acc2[mt][nt][r] + bias;
                table[(size_t)(base + row) * Cn + col] = s_lds[row][col] + gate * v;
            }
    }
}

extern "C" void kernel_launch(void* const* d_in, const int* in_sizes, int n_in,
                              void* d_out, int out_size, void* d_ws, size_t ws_size,
                              hipStream_t stream) {
    const float* x_BLD   = (const float*)d_in[0];
    const float* c_BD    = (const float*)d_in[1];
    const float* embed_w = (const float*)d_in[2];
    const float* pos_w   = (const float*)d_in[3];
    const float* bins    = (const float*)d_in[4];
    const float* ada_w   = (const float*)d_in[5];
    const float* ada_b   = (const float*)d_in[6];
    const float* ln_g    = (const float*)d_in[7];
    const float* ln_b    = (const float*)d_in[8];
    const float* fc1_w   = (const float*)d_in[9];
    const float* fc1_b   = (const float*)d_in[10];
    const float* fc2_w   = (const float*)d_in[11];
    const float* fc2_b   = (const float*)d_in[12];
    float* out = (float*)d_out;

    char* ws = (char*)d_ws;
    float* mod   = (float*)ws;                               // 8 KB
    short* fc1bf = (short*)(ws + 8192);                      // 512 KB
    short* fc2bf = (short*)(ws + 8192 + 524288);             // 512 KB
    short* hbuf  = (short*)(ws + 1056768);                   // 8 MB
    short* gbuf  = (short*)(ws + 26222592);                  // 32 MB
    float* tableA= (float*)(ws + 59777024);                  // 16 MB
    const size_t needA = 76554240;
    const size_t needB = 8192 + 2 * (size_t)Cn * H1 * sizeof(short)
                       + (size_t)NCOMBO * Cn * sizeof(float);

    mod_kernel<<<(Bn * 3 * Cn) / 256, 256, 0, stream>>>(c_BD, ada_w, ada_b, mod);
    cvt_kernel<<<(Cn * H1 / 4 + 255) / 256, 256, 0, stream>>>(fc1_w, fc1bf, Cn * H1);
    cvt_kernel<<<(Cn * H1 / 4 + 255) / 256, 256, 0, stream>>>(fc2_w, fc2bf, Cn * H1);

    if (ws_size >= needA) {
        ln_kernel<<<NCOMBO / 8, 256, 0, stream>>>(
            embed_w, pos_w, ln_g, ln_b, mod, hbuf);
        gemm1_kernel<<<(NCOMBO / 128) * (H1 / 128), 256, 0, stream>>>(
            hbuf, fc1bf, fc1_b, gbuf);
        gemm2_kernel<<<(NCOMBO / 64) * (Cn / 128), 256, 0, stream>>>(
            gbuf, fc2bf, fc2_b, embed_w, pos_w, mod, tableA);
        gather_kernel<<<Bn * Ln * 4, 256, 0, stream>>>(x_BLD, bins, tableA, out);
    } else {
        float* tableB = (float*)(ws + 8192 + 2 * (size_t)Cn * H1 * sizeof(short));
        (void)needB;
        table_mfma_kernel<<<NCOMBO / TROWS, 256, 0, stream>>>(
            embed_w, pos_w, ln_g, ln_b, fc1bf, fc1_b, fc2bf, fc2_b, mod, tableB);
        gather_kernel<<<Bn * Ln * 4, 256, 0, stream>>>(x_BLD, bins, tableB, out);
    }
}